// Round 2
// baseline (204.729 us; speedup 1.0000x reference)
//
#include <hip/hip_runtime.h>
#include <hip/hip_bf16.h>

// B=2, S=2048, D=1024, H=16, DH=64
#define S_LEN   2048
#define D_MODEL 1024
#define NHEAD   16
#define DHEAD   64
#define M_ROWS  4096   // B*S
#define BHEADS  32     // B*H
#define MEG     1048576

typedef __attribute__((ext_vector_type(8)))  short short8;   // 8 bf16 (4 VGPRs)
typedef __attribute__((ext_vector_type(4)))  float f32x4;
typedef __attribute__((ext_vector_type(16))) float f32x16;
typedef __attribute__((ext_vector_type(4)))  unsigned short us4;
typedef __attribute__((ext_vector_type(2)))  unsigned int uint2v;
typedef __attribute__((ext_vector_type(4)))  unsigned int uint4v;

// fast native exp2 (single v_exp_f32) from ROCm device libs
extern "C" __device__ float __ocml_native_exp2_f32(float);

// fp32 -> bf16 round-to-nearest-even
__device__ __forceinline__ unsigned short f2b(float f) {
    unsigned int u = __builtin_bit_cast(unsigned int, f);
    return (unsigned short)((u + 0x7FFFu + ((u >> 16) & 1u)) >> 16);
}

// pack two fp32 -> two bf16 in one dword (lo in low short)
__device__ __forceinline__ unsigned int pk2b(float lo, float hi) {
    unsigned int u0 = __builtin_bit_cast(unsigned int, lo) + 0x8000u;
    unsigned int u1 = __builtin_bit_cast(unsigned int, hi) + 0x8000u;
    return __builtin_amdgcn_perm(u1, u0, 0x07060302u);
}

__device__ __forceinline__ float b2f(unsigned short b) {
    return __builtin_bit_cast(float, (unsigned int)b << 16);
}

// async global->LDS, 16B per lane; LDS dest = wave-uniform base + lane*16
#define GLOAD16(gp, lp) __builtin_amdgcn_global_load_lds(                     \
        (const __attribute__((address_space(1))) void*)(gp),                  \
        (__attribute__((address_space(3))) void*)(lp), 16, 0, 0)

// Bank swizzle: logical 16B sub-block sb of row r lives at phys sb ^ ((r>>1)&3).
#define STAGE_OFS(lane) ((((lane) & 3) ^ (((lane) >> 3) & 3)) * 8)

// ---------------------------------------------------------------------------
// Fused prep: z<4 -> transpose W z to bf16 Wt[n][k]; z==4 -> convert x to bf16
// ---------------------------------------------------------------------------
__global__ __launch_bounds__(256) void prep(
    const float* __restrict__ x, unsigned short* __restrict__ xb,
    const float* __restrict__ Wq, const float* __restrict__ Wk,
    const float* __restrict__ Wv, const float* __restrict__ Wo,
    unsigned short* __restrict__ Wqt, unsigned short* __restrict__ Wkt,
    unsigned short* __restrict__ Wvt, unsigned short* __restrict__ Wot)
{
    const int z = blockIdx.z;
    const int tx = threadIdx.x, ty = threadIdx.y;     // 32 x 8
    if (z == 4) {
        const int blk = blockIdx.y * 32 + blockIdx.x;     // 0..1023
        const int base = (blk * 256 + ty * 32 + tx) * 4;
        #pragma unroll
        for (int r = 0; r < 4; ++r) {
            const int i = base + r * (M_ROWS * D_MODEL / 4);
            const float4 v = *(const float4*)&x[i];
            us4 o;
            o.x = f2b(v.x); o.y = f2b(v.y); o.z = f2b(v.z); o.w = f2b(v.w);
            *(us4*)&xb[i] = o;
        }
        return;
    }
    __shared__ float tile[32][33];
    const float* W = z == 0 ? Wq : (z == 1 ? Wk : (z == 2 ? Wv : Wo));
    unsigned short* Wt = z == 0 ? Wqt : (z == 1 ? Wkt : (z == 2 ? Wvt : Wot));
    const int n0 = blockIdx.x * 32, k0 = blockIdx.y * 32;
    #pragma unroll
    for (int i = 0; i < 4; ++i)
        tile[ty + i * 8][tx] = W[(size_t)(k0 + ty + i * 8) * D_MODEL + n0 + tx];
    __syncthreads();
    #pragma unroll
    for (int i = 0; i < 4; ++i)
        Wt[(size_t)(n0 + ty + i * 8) * D_MODEL + k0 + tx] = f2b(tile[tx][ty + i * 8]);
}

// ---------------------------------------------------------------------------
// Fused Q/K/V projection GEMM (z = 0/1/2), double-buffered single-barrier.
// ---------------------------------------------------------------------------
__global__ __launch_bounds__(256) void gemm_qkv(
    const unsigned short* __restrict__ xb,
    const unsigned short* __restrict__ Wqt, const unsigned short* __restrict__ Wkt,
    const unsigned short* __restrict__ Wvt,
    const float* __restrict__ bq, const float* __restrict__ bk,
    const float* __restrict__ bv,
    unsigned short* __restrict__ Qb, unsigned short* __restrict__ Kb,
    unsigned short* __restrict__ Vt)
{
    __shared__ unsigned short As[2][128][32];
    __shared__ unsigned short Bs[2][128][32];

    const int z = blockIdx.z;
    const unsigned short* Wt = z == 0 ? Wqt : (z == 1 ? Wkt : Wvt);
    const float* bias = z == 0 ? bq : (z == 1 ? bk : bv);

    const int t = threadIdx.x, lane = t & 63, w = t >> 6;
    const int wm = w >> 1, wn = w & 1;
    const int bm = blockIdx.y * 128, bn = blockIdx.x * 128;
    const int lr = lane >> 2, lc = STAGE_OFS(lane);
    const int lm = lane & 15, quad = lane >> 4;
    const int qo = (quad ^ ((lm >> 1) & 3)) * 8;      // swizzled frag offset

    f32x4 acc[4][4] = {};

    #pragma unroll
    for (int i = 0; i < 2; ++i) {
        const int c = 2 * w + i;
        GLOAD16(xb + (size_t)(bm + c * 16 + lr) * D_MODEL + lc, &As[0][c * 16][0]);
        GLOAD16(Wt + (size_t)(bn + c * 16 + lr) * D_MODEL + lc, &Bs[0][c * 16][0]);
    }
    __syncthreads();

    for (int it = 0; it < 32; ++it) {
        const int cur = it & 1;
        if (it + 1 < 32) {
            const int kt = (it + 1) * 32;
            #pragma unroll
            for (int i = 0; i < 2; ++i) {
                const int c = 2 * w + i;
                GLOAD16(xb + (size_t)(bm + c * 16 + lr) * D_MODEL + kt + lc,
                        &As[cur ^ 1][c * 16][0]);
                GLOAD16(Wt + (size_t)(bn + c * 16 + lr) * D_MODEL + kt + lc,
                        &Bs[cur ^ 1][c * 16][0]);
            }
        }

        short8 af[4], bfr[4];
        #pragma unroll
        for (int mi = 0; mi < 4; ++mi)
            af[mi] = *(const short8*)&As[cur][wm * 64 + mi * 16 + lm][qo];
        #pragma unroll
        for (int ni = 0; ni < 4; ++ni)
            bfr[ni] = *(const short8*)&Bs[cur][wn * 64 + ni * 16 + lm][qo];
        #pragma unroll
        for (int mi = 0; mi < 4; ++mi)
            #pragma unroll
            for (int ni = 0; ni < 4; ++ni)
                acc[mi][ni] = __builtin_amdgcn_mfma_f32_16x16x32_bf16(
                    af[mi], bfr[ni], acc[mi][ni], 0, 0, 0);

        __syncthreads();
    }

    float bb[4];
    #pragma unroll
    for (int ni = 0; ni < 4; ++ni)
        bb[ni] = bias[bn + wn * 64 + ni * 16 + lm];
    const float scale = (z == 0) ? 0.18033688011112042f : 1.0f;  // (1/8)*log2e

    if (z < 2) {
        unsigned short* Out = (z == 0) ? Qb : Kb;
        #pragma unroll
        for (int mi = 0; mi < 4; ++mi)
            #pragma unroll
            for (int r = 0; r < 4; ++r) {
                const int row = bm + wm * 64 + mi * 16 + quad * 4 + r;
                const int b = row >> 11, s = row & 2047;
                #pragma unroll
                for (int ni = 0; ni < 4; ++ni) {
                    const int col = bn + wn * 64 + ni * 16 + lm;
                    const int h = col >> 6, d = col & 63;
                    Out[(((size_t)(b * NHEAD + h)) * S_LEN + s) * DHEAD + d] =
                        f2b((acc[mi][ni][r] + bb[ni]) * scale);
                }
            }
    } else {
        #pragma unroll
        for (int mi = 0; mi < 4; ++mi) {
            const int row0 = bm + wm * 64 + mi * 16 + quad * 4;
            const int b = row0 >> 11, s0 = row0 & 2047;
            #pragma unroll
            for (int ni = 0; ni < 4; ++ni) {
                const int col = bn + wn * 64 + ni * 16 + lm;
                const int h = col >> 6, d = col & 63;
                us4 pk;
                pk.x = f2b(acc[mi][ni][0] + bb[ni]);
                pk.y = f2b(acc[mi][ni][1] + bb[ni]);
                pk.z = f2b(acc[mi][ni][2] + bb[ni]);
                pk.w = f2b(acc[mi][ni][3] + bb[ni]);
                *(us4*)&Vt[(((size_t)(b * NHEAD + h)) * DHEAD + d) * S_LEN + s0] = pk;
            }
        }
    }
}

// ---------------------------------------------------------------------------
// Output projection: 64x128 tile, double-buffered single-barrier K-loop.
// ---------------------------------------------------------------------------
__global__ __launch_bounds__(256) void gemm_out(
    const unsigned short* __restrict__ Ab, const unsigned short* __restrict__ Wot,
    const float* __restrict__ bo, float* __restrict__ out)
{
    __shared__ unsigned short As[2][64][32];
    __shared__ unsigned short Bs[2][128][32];

    const int t = threadIdx.x, lane = t & 63, w = t >> 6;
    const int wm = w & 1, wn = w >> 1;
    const int bm = blockIdx.y * 64, bn = blockIdx.x * 128;
    const int lr = lane >> 2, lc = STAGE_OFS(lane);
    const int lm = lane & 15, quad = lane >> 4;
    const int qo = (quad ^ ((lm >> 1) & 3)) * 8;

    f32x4 acc[2][4] = {};

    GLOAD16(Ab + (size_t)(bm + w * 16 + lr) * D_MODEL + lc, &As[0][w * 16][0]);
    #pragma unroll
    for (int i = 0; i < 2; ++i)
        GLOAD16(Wot + (size_t)(bn + w * 32 + i * 16 + lr) * D_MODEL + lc,
                &Bs[0][w * 32 + i * 16][0]);
    __syncthreads();

    for (int it = 0; it < 32; ++it) {
        const int cur = it & 1;
        if (it + 1 < 32) {
            const int kt = (it + 1) * 32;
            GLOAD16(Ab + (size_t)(bm + w * 16 + lr) * D_MODEL + kt + lc,
                    &As[cur ^ 1][w * 16][0]);
            #pragma unroll
            for (int i = 0; i < 2; ++i)
                GLOAD16(Wot + (size_t)(bn + w * 32 + i * 16 + lr) * D_MODEL + kt + lc,
                        &Bs[cur ^ 1][w * 32 + i * 16][0]);
        }

        short8 af[2], bfr[4];
        #pragma unroll
        for (int mi = 0; mi < 2; ++mi)
            af[mi] = *(const short8*)&As[cur][wm * 32 + mi * 16 + lm][qo];
        #pragma unroll
        for (int ni = 0; ni < 4; ++ni)
            bfr[ni] = *(const short8*)&Bs[cur][wn * 64 + ni * 16 + lm][qo];
        #pragma unroll
        for (int mi = 0; mi < 2; ++mi)
            #pragma unroll
            for (int ni = 0; ni < 4; ++ni)
                acc[mi][ni] = __builtin_amdgcn_mfma_f32_16x16x32_bf16(
                    af[mi], bfr[ni], acc[mi][ni], 0, 0, 0);

        __syncthreads();
    }

    float bb[4];
    #pragma unroll
    for (int ni = 0; ni < 4; ++ni)
        bb[ni] = bo[bn + wn * 64 + ni * 16 + lm];

    #pragma unroll
    for (int mi = 0; mi < 2; ++mi)
        #pragma unroll
        for (int r = 0; r < 4; ++r) {
            const int row = bm + wm * 32 + mi * 16 + quad * 4 + r;
            #pragma unroll
            for (int ni = 0; ni < 4; ++ni) {
                const int col = bn + wn * 64 + ni * 16 + lm;
                out[(size_t)row * D_MODEL + col] = acc[mi][ni][r] + bb[ni];
            }
        }
}

// ---------------------------------------------------------------------------
// MFMA flash attention, S^T form, 32x32x16, bank-swizzled LDS, SPLIT-S:
// grid z in {0,1} -> this block covers k in [z*1024, z*1024+1024). Fixed
// max=0 makes partials additive: write unnormalized O (bf16) + l (fp32) to
// workspace; attn_reduce combines.
//
// R2: the P transpose no longer round-trips through LDS at all. After the
// swapped QK^T, lane (q5,hi) holds P[q5][k] for k in {32mt+8g+4hi+j}. The PV
// A-frag for instance c needs lane (q5,hi') to hold k = 16c+8hi'+{0..7}; the
// missing half lives in the partner lane (q5,1-hi'). Two
// v_permlane32_swap_b32 per instance move it: with dst = pk(p[0],p[1]) etc.
// (groups 2pp / 2pp+1), out0 = A-frag reg r0 (and r1), out1 = r2 (r3), for
// BOTH lane halves at once. Kills 8 ds_write_b64 + 4 ds_read_b128 per iter
// (the entire Ps bank-conflict source, ~20% of cycles in R0/R1).
// LDS = Qs 16K + Ks 8K + Vs 8K = 32K -> 4 blocks/CU. No setprio (m190:
// neutral/negative on barrier-locked loops).
// ---------------------------------------------------------------------------
__global__ __launch_bounds__(256, 4) void attn_mfma(
    const unsigned short* __restrict__ Q, const unsigned short* __restrict__ K,
    const unsigned short* __restrict__ V,
    unsigned short* __restrict__ Opart, float* __restrict__ Lpart)
{
    __shared__ __align__(16) unsigned short Qs[2][128][32];  // 16 KB
    __shared__ unsigned short Ks[2][64][32];   // [d-half][k][d32]
    __shared__ unsigned short Vs[2][64][32];   // [s-half][d][s32]

    const int t = threadIdx.x, lane = t & 63, w = t >> 6;
    const int q5 = lane & 31, hi = lane >> 5;
    const int lr = lane >> 2, lcs = STAGE_OFS(lane);
    const int q0 = blockIdx.x * 128, bh = blockIdx.y, split = blockIdx.z;
    const int k_base = split * (S_LEN / 2);
    const int sw = (q5 >> 1) & 3;              // row-swizzle for frag reads
    int sbo[4];
    #pragma unroll
    for (int sb = 0; sb < 4; ++sb) sbo[sb] = (sb ^ sw) * 8;

    const unsigned short* Qh = Q + (size_t)bh * (S_LEN * DHEAD);
    const unsigned short* Kh = K + (size_t)bh * (S_LEN * DHEAD);
    const unsigned short* Vh = V + (size_t)bh * (DHEAD * S_LEN);

    // stage Q tile once: wave w stages rows w*32 .. w*32+31, both d-halves
    #pragma unroll
    for (int i = 0; i < 2; ++i)
        #pragma unroll
        for (int c = 0; c < 2; ++c)
            GLOAD16(Qh + (size_t)(q0 + w * 32 + c * 16 + lr) * DHEAD + i * 32 + lcs,
                    &Qs[i][w * 32 + c * 16][0]);
    __syncthreads();

    // hoist Q B-frags into registers
    short8 qf[4];
    #pragma unroll
    for (int c = 0; c < 4; ++c)
        qf[c] = *(const short8*)&Qs[c >> 1][w * 32 + q5][sbo[(c & 1) * 2 + hi]];

    f32x16 acc[2] = {};   // O strip: [d-tile][16 regs], row=q, col=d
    float2 l2a = {0.f, 0.f}, l2b = {0.f, 0.f};

    for (int it = 0; it < 16; ++it) {
        const int kt = k_base + it * 64;
        __syncthreads();                       // prev compute done
        #pragma unroll
        for (int i = 0; i < 2; ++i) {
            GLOAD16(Kh + (size_t)(kt + w * 16 + lr) * DHEAD + i * 32 + lcs,
                    &Ks[i][w * 16][0]);
            GLOAD16(Vh + (size_t)(w * 16 + lr) * S_LEN + kt + i * 32 + lcs,
                    &Vs[i][w * 16][0]);
        }
        __syncthreads();                       // tiles ready

        // ---- S^T: rows k = mt*32 + C-pattern, col q = q5 ----
        f32x16 sf[2] = {};
        #pragma unroll
        for (int c = 0; c < 4; ++c) {
            #pragma unroll
            for (int mt = 0; mt < 2; ++mt) {
                const short8 kf =
                    *(const short8*)&Ks[c >> 1][mt * 32 + q5][sbo[(c & 1) * 2 + hi]];
                sf[mt] = __builtin_amdgcn_mfma_f32_32x32x16_bf16(kf, qf[c], sf[mt], 0, 0, 0);
            }
        }

        // ---- PV, fully in-register: per instance c, exp 8 P-values,
        // pack to 4 dwords, 2 permlane32_swap -> exact A-frag; MFMA x2 ----
        #pragma unroll
        for (int c = 0; c < 4; ++c) {
            const int mt = c >> 1, pp = c & 1;
            float p[8];
            #pragma unroll
            for (int e = 0; e < 8; ++e)
                p[e] = __ocml_native_exp2_f32(sf[mt][pp * 8 + e]);
            l2a.x += p[0]; l2a.y += p[1]; l2b.x += p[2]; l2b.y += p[3];
            l2a.x += p[4]; l2a.y += p[5]; l2b.x += p[6]; l2b.y += p[7];
            const unsigned int dA = pk2b(p[0], p[1]);
            const unsigned int dB = pk2b(p[2], p[3]);
            const unsigned int sA = pk2b(p[4], p[5]);
            const unsigned int sB = pk2b(p[6], p[7]);
            const uint2v wA = __builtin_amdgcn_permlane32_swap(dA, sA, false, false);
            const uint2v wB = __builtin_amdgcn_permlane32_swap(dB, sB, false, false);
            uint4v wrds;
            wrds.x = wA.x; wrds.y = wB.x; wrds.z = wA.y; wrds.w = wB.y;
            const short8 pf = __builtin_bit_cast(short8, wrds);
            #pragma unroll
            for (int nt = 0; nt < 2; ++nt) {
                const short8 vf =
                    *(const short8*)&Vs[c >> 1][nt * 32 + q5][sbo[(c & 1) * 2 + hi]];
                acc[nt] = __builtin_amdgcn_mfma_f32_32x32x16_bf16(pf, vf, acc[nt], 0, 0, 0);
            }
        }
    }

    // ---- epilogue: write unnormalized partial O (bf16) + partial l (fp32)
    float l_acc = (l2a.x + l2a.y) + (l2b.x + l2b.y);
    l_acc += __shfl_xor(l_acc, 32);            // full 1024-k sum for q=q5
    const size_t pbase = ((size_t)(split * BHEADS + bh)) * S_LEN;
    if (hi == 0)
        Lpart[pbase + q0 + w * 32 + q5] = l_acc;
    #pragma unroll
    for (int reg = 0; reg < 16; ++reg) {
        const int row = (reg & 3) + 8 * (reg >> 2) + 4 * hi;
        const size_t obase = (pbase + q0 + w * 32 + row) * DHEAD;
        Opart[obase + q5]      = f2b(acc[0][reg]);
        Opart[obase + 32 + q5] = f2b(acc[1][reg]);
    }
}

// ---------------------------------------------------------------------------
// Combine split partials: Cxb = (O0 + O1) / (l0 + l1), bf16 [B,S,D] layout.
// ---------------------------------------------------------------------------
__global__ __launch_bounds__(256) void attn_reduce(
    const unsigned short* __restrict__ Op, const float* __restrict__ Lp,
    unsigned short* __restrict__ Cx)
{
    const int idx = blockIdx.x * 256 + threadIdx.x;
    const int gi = idx * 4;                    // elem index within one split
    const int bh = gi >> 17;                   // / (S_LEN*DHEAD)
    const int rem = gi & (S_LEN * DHEAD - 1);
    const int s = rem >> 6, d = rem & 63;
    const size_t o0 = (size_t)bh * (S_LEN * DHEAD) + rem;
    const size_t o1 = o0 + (size_t)BHEADS * S_LEN * DHEAD;
    const us4 a = *(const us4*)&Op[o0];
    const us4 c = *(const us4*)&Op[o1];
    const float inv = 1.f / (Lp[bh * S_LEN + s] + Lp[BHEADS * S_LEN + bh * S_LEN + s]);
    us4 o;
    o.x = f2b((b2f(a.x) + b2f(c.x)) * inv);
    o.y = f2b((b2f(a.y) + b2f(c.y)) * inv);
    o.z = f2b((b2f(a.z) + b2f(c.z)) * inv);
    o.w = f2b((b2f(a.w) + b2f(c.w)) * inv);
    const int b = bh >> 4, h = bh & 15;
    *(us4*)&Cx[((size_t)(b * S_LEN + s)) * D_MODEL + h * DHEAD + d] = o;
}

// ---------------------------------------------------------------------------
extern "C" void kernel_launch(void* const* d_in, const int* in_sizes, int n_in,
                              void* d_out, int out_size, void* d_ws, size_t ws_size,
                              hipStream_t stream)
{
    const float* x  = (const float*)d_in[0];
    const float* Wq = (const float*)d_in[1];
    const float* bq = (const float*)d_in[2];
    const float* Wk = (const float*)d_in[3];
    const float* bk = (const float*)d_in[4];
    const float* Wv = (const float*)d_in[5];
    const float* bv = (const float*)d_in[6];
    const float* Wo = (const float*)d_in[7];
    const float* bo = (const float*)d_in[8];
    float* out = (float*)d_out;

    // ws layout (ushort units). Opart (8M ushorts, 16MB) ALIASES the region
    // [xb, Wqt, Wkt, Wvt, pad] -- all dead once attn_mfma runs. Wot lives at
    // the front so gemm_out can still read it after attn clobbers the rest.
    unsigned short* base = (unsigned short*)d_ws;
    unsigned short* Wot   = base;                   //  0M .. 1M
    unsigned short* Qb    = base + 1 * MEG;         //  1M .. 5M
    unsigned short* Kb    = base + 5 * MEG;         //  5M .. 9M
    unsigned short* Vt    = base + 9 * MEG;         //  9M ..13M
    unsigned short* Cxb   = base + 13 * MEG;        // 13M ..17M
    unsigned short* xb    = base + 17 * MEG;        // 17M ..21M
    unsigned short* Wqt   = base + 21 * MEG;        // 21M ..22M
    unsigned short* Wkt   = base + 22 * MEG;        // 22M ..23M
    unsigned short* Wvt   = base + 23 * MEG;        // 23M ..24M (pad 24M..25M)
    unsigned short* Opart = xb;                     // 17M ..25M (8M ushorts)
    float*          Lpart = (float*)(base + 25 * MEG);  // 512 KB

    prep<<<dim3(32, 32, 5), dim3(32, 8), 0, stream>>>(
        x, xb, Wq, Wk, Wv, Wo, Wqt, Wkt, Wvt, Wot);

    gemm_qkv<<<dim3(D_MODEL / 128, M_ROWS / 128, 3), dim3(256), 0, stream>>>(
        xb, Wqt, Wkt, Wvt, bq, bk, bv, Qb, Kb, Vt);

    attn_mfma<<<dim3(S_LEN / 128, BHEADS, 2), dim3(256), 0, stream>>>(
        Qb, Kb, Vt, Opart, Lpart);

    attn_reduce<<<dim3(BHEADS * S_LEN * DHEAD / 1024), dim3(256), 0, stream>>>(
        Opart, Lpart, Cxb);

    gemm_out<<<dim3(D_MODEL / 128, M_ROWS / 64), dim3(256), 0, stream>>>(
        Cxb, Wot, bo, out);
}

// Round 4
// 199.267 us; speedup vs baseline: 1.0274x; 1.0274x over previous
//
#include <hip/hip_runtime.h>
#include <hip/hip_bf16.h>

// B=2, S=2048, D=1024, H=16, DH=64
#define S_LEN   2048
#define D_MODEL 1024
#define NHEAD   16
#define DHEAD   64
#define M_ROWS  4096   // B*S
#define BHEADS  32     // B*H
#define MEG     1048576

typedef __attribute__((ext_vector_type(8)))  short short8;   // 8 bf16 (4 VGPRs)
typedef __attribute__((ext_vector_type(4)))  float f32x4;
typedef __attribute__((ext_vector_type(16))) float f32x16;
typedef __attribute__((ext_vector_type(4)))  unsigned short us4;
typedef __attribute__((ext_vector_type(2)))  unsigned int uint2v;
typedef __attribute__((ext_vector_type(4)))  unsigned int uint4v;

// fast native exp2 (single v_exp_f32) from ROCm device libs
extern "C" __device__ float __ocml_native_exp2_f32(float);

// fp32 -> bf16 round-to-nearest-even
__device__ __forceinline__ unsigned short f2b(float f) {
    unsigned int u = __builtin_bit_cast(unsigned int, f);
    return (unsigned short)((u + 0x7FFFu + ((u >> 16) & 1u)) >> 16);
}

// pack two fp32 -> two bf16 in one dword (lo in low short)
__device__ __forceinline__ unsigned int pk2b(float lo, float hi) {
    unsigned int u0 = __builtin_bit_cast(unsigned int, lo) + 0x8000u;
    unsigned int u1 = __builtin_bit_cast(unsigned int, hi) + 0x8000u;
    return __builtin_amdgcn_perm(u1, u0, 0x07060302u);
}

__device__ __forceinline__ float b2f(unsigned short b) {
    return __builtin_bit_cast(float, (unsigned int)b << 16);
}

// async global->LDS, 16B per lane; LDS dest = wave-uniform base + lane*16
#define GLOAD16(gp, lp) __builtin_amdgcn_global_load_lds(                     \
        (const __attribute__((address_space(1))) void*)(gp),                  \
        (__attribute__((address_space(3))) void*)(lp), 16, 0, 0)

// Bank swizzle: logical 16B sub-block sb of row r lives at phys sb ^ ((r>>1)&3).
#define STAGE_OFS(lane) ((((lane) & 3) ^ (((lane) >> 3) & 3)) * 8)

// ---------------------------------------------------------------------------
// Fused prep: z<4 -> transpose W z to bf16 Wt[n][k]; z==4 -> convert x to bf16
// ---------------------------------------------------------------------------
__global__ __launch_bounds__(256) void prep(
    const float* __restrict__ x, unsigned short* __restrict__ xb,
    const float* __restrict__ Wq, const float* __restrict__ Wk,
    const float* __restrict__ Wv, const float* __restrict__ Wo,
    unsigned short* __restrict__ Wqt, unsigned short* __restrict__ Wkt,
    unsigned short* __restrict__ Wvt, unsigned short* __restrict__ Wot)
{
    const int z = blockIdx.z;
    const int tx = threadIdx.x, ty = threadIdx.y;     // 32 x 8
    if (z == 4) {
        const int blk = blockIdx.y * 32 + blockIdx.x;     // 0..1023
        const int base = (blk * 256 + ty * 32 + tx) * 4;
        #pragma unroll
        for (int r = 0; r < 4; ++r) {
            const int i = base + r * (M_ROWS * D_MODEL / 4);
            const float4 v = *(const float4*)&x[i];
            us4 o;
            o.x = f2b(v.x); o.y = f2b(v.y); o.z = f2b(v.z); o.w = f2b(v.w);
            *(us4*)&xb[i] = o;
        }
        return;
    }
    __shared__ float tile[32][33];
    const float* W = z == 0 ? Wq : (z == 1 ? Wk : (z == 2 ? Wv : Wo));
    unsigned short* Wt = z == 0 ? Wqt : (z == 1 ? Wkt : (z == 2 ? Wvt : Wot));
    const int n0 = blockIdx.x * 32, k0 = blockIdx.y * 32;
    #pragma unroll
    for (int i = 0; i < 4; ++i)
        tile[ty + i * 8][tx] = W[(size_t)(k0 + ty + i * 8) * D_MODEL + n0 + tx];
    __syncthreads();
    #pragma unroll
    for (int i = 0; i < 4; ++i)
        Wt[(size_t)(n0 + ty + i * 8) * D_MODEL + k0 + tx] = f2b(tile[tx][ty + i * 8]);
}

// ---------------------------------------------------------------------------
// Fused Q/K/V projection GEMM (z = 0/1/2), double-buffered single-barrier.
// ---------------------------------------------------------------------------
__global__ __launch_bounds__(256) void gemm_qkv(
    const unsigned short* __restrict__ xb,
    const unsigned short* __restrict__ Wqt, const unsigned short* __restrict__ Wkt,
    const unsigned short* __restrict__ Wvt,
    const float* __restrict__ bq, const float* __restrict__ bk,
    const float* __restrict__ bv,
    unsigned short* __restrict__ Qb, unsigned short* __restrict__ Kb,
    unsigned short* __restrict__ Vt)
{
    __shared__ unsigned short As[2][128][32];
    __shared__ unsigned short Bs[2][128][32];

    const int z = blockIdx.z;
    const unsigned short* Wt = z == 0 ? Wqt : (z == 1 ? Wkt : Wvt);
    const float* bias = z == 0 ? bq : (z == 1 ? bk : bv);

    const int t = threadIdx.x, lane = t & 63, w = t >> 6;
    const int wm = w >> 1, wn = w & 1;
    const int bm = blockIdx.y * 128, bn = blockIdx.x * 128;
    const int lr = lane >> 2, lc = STAGE_OFS(lane);
    const int lm = lane & 15, quad = lane >> 4;
    const int qo = (quad ^ ((lm >> 1) & 3)) * 8;      // swizzled frag offset

    f32x4 acc[4][4] = {};

    #pragma unroll
    for (int i = 0; i < 2; ++i) {
        const int c = 2 * w + i;
        GLOAD16(xb + (size_t)(bm + c * 16 + lr) * D_MODEL + lc, &As[0][c * 16][0]);
        GLOAD16(Wt + (size_t)(bn + c * 16 + lr) * D_MODEL + lc, &Bs[0][c * 16][0]);
    }
    __syncthreads();

    for (int it = 0; it < 32; ++it) {
        const int cur = it & 1;
        if (it + 1 < 32) {
            const int kt = (it + 1) * 32;
            #pragma unroll
            for (int i = 0; i < 2; ++i) {
                const int c = 2 * w + i;
                GLOAD16(xb + (size_t)(bm + c * 16 + lr) * D_MODEL + kt + lc,
                        &As[cur ^ 1][c * 16][0]);
                GLOAD16(Wt + (size_t)(bn + c * 16 + lr) * D_MODEL + kt + lc,
                        &Bs[cur ^ 1][c * 16][0]);
            }
        }

        short8 af[4], bfr[4];
        #pragma unroll
        for (int mi = 0; mi < 4; ++mi)
            af[mi] = *(const short8*)&As[cur][wm * 64 + mi * 16 + lm][qo];
        #pragma unroll
        for (int ni = 0; ni < 4; ++ni)
            bfr[ni] = *(const short8*)&Bs[cur][wn * 64 + ni * 16 + lm][qo];
        #pragma unroll
        for (int mi = 0; mi < 4; ++mi)
            #pragma unroll
            for (int ni = 0; ni < 4; ++ni)
                acc[mi][ni] = __builtin_amdgcn_mfma_f32_16x16x32_bf16(
                    af[mi], bfr[ni], acc[mi][ni], 0, 0, 0);

        __syncthreads();
    }

    float bb[4];
    #pragma unroll
    for (int ni = 0; ni < 4; ++ni)
        bb[ni] = bias[bn + wn * 64 + ni * 16 + lm];
    const float scale = (z == 0) ? 0.18033688011112042f : 1.0f;  // (1/8)*log2e

    if (z < 2) {
        unsigned short* Out = (z == 0) ? Qb : Kb;
        #pragma unroll
        for (int mi = 0; mi < 4; ++mi)
            #pragma unroll
            for (int r = 0; r < 4; ++r) {
                const int row = bm + wm * 64 + mi * 16 + quad * 4 + r;
                const int b = row >> 11, s = row & 2047;
                #pragma unroll
                for (int ni = 0; ni < 4; ++ni) {
                    const int col = bn + wn * 64 + ni * 16 + lm;
                    const int h = col >> 6, d = col & 63;
                    Out[(((size_t)(b * NHEAD + h)) * S_LEN + s) * DHEAD + d] =
                        f2b((acc[mi][ni][r] + bb[ni]) * scale);
                }
            }
    } else {
        #pragma unroll
        for (int mi = 0; mi < 4; ++mi) {
            const int row0 = bm + wm * 64 + mi * 16 + quad * 4;
            const int b = row0 >> 11, s0 = row0 & 2047;
            #pragma unroll
            for (int ni = 0; ni < 4; ++ni) {
                const int col = bn + wn * 64 + ni * 16 + lm;
                const int h = col >> 6, d = col & 63;
                us4 pk;
                pk.x = f2b(acc[mi][ni][0] + bb[ni]);
                pk.y = f2b(acc[mi][ni][1] + bb[ni]);
                pk.z = f2b(acc[mi][ni][2] + bb[ni]);
                pk.w = f2b(acc[mi][ni][3] + bb[ni]);
                *(us4*)&Vt[(((size_t)(b * NHEAD + h)) * DHEAD + d) * S_LEN + s0] = pk;
            }
        }
    }
}

// ---------------------------------------------------------------------------
// Output projection: 64x128 tile, double-buffered single-barrier K-loop.
// ---------------------------------------------------------------------------
__global__ __launch_bounds__(256) void gemm_out(
    const unsigned short* __restrict__ Ab, const unsigned short* __restrict__ Wot,
    const float* __restrict__ bo, float* __restrict__ out)
{
    __shared__ unsigned short As[2][64][32];
    __shared__ unsigned short Bs[2][128][32];

    const int t = threadIdx.x, lane = t & 63, w = t >> 6;
    const int wm = w & 1, wn = w >> 1;
    const int bm = blockIdx.y * 64, bn = blockIdx.x * 128;
    const int lr = lane >> 2, lc = STAGE_OFS(lane);
    const int lm = lane & 15, quad = lane >> 4;
    const int qo = (quad ^ ((lm >> 1) & 3)) * 8;

    f32x4 acc[2][4] = {};

    GLOAD16(Ab + (size_t)(bm + w * 16 + lr) * D_MODEL + lc, &As[0][w * 16][0]);
    #pragma unroll
    for (int i = 0; i < 2; ++i)
        GLOAD16(Wot + (size_t)(bn + w * 32 + i * 16 + lr) * D_MODEL + lc,
                &Bs[0][w * 32 + i * 16][0]);
    __syncthreads();

    for (int it = 0; it < 32; ++it) {
        const int cur = it & 1;
        if (it + 1 < 32) {
            const int kt = (it + 1) * 32;
            GLOAD16(Ab + (size_t)(bm + w * 16 + lr) * D_MODEL + kt + lc,
                    &As[cur ^ 1][w * 16][0]);
            #pragma unroll
            for (int i = 0; i < 2; ++i)
                GLOAD16(Wot + (size_t)(bn + w * 32 + i * 16 + lr) * D_MODEL + kt + lc,
                        &Bs[cur ^ 1][w * 32 + i * 16][0]);
        }

        short8 af[2], bfr[4];
        #pragma unroll
        for (int mi = 0; mi < 2; ++mi)
            af[mi] = *(const short8*)&As[cur][wm * 32 + mi * 16 + lm][qo];
        #pragma unroll
        for (int ni = 0; ni < 4; ++ni)
            bfr[ni] = *(const short8*)&Bs[cur][wn * 64 + ni * 16 + lm][qo];
        #pragma unroll
        for (int mi = 0; mi < 2; ++mi)
            #pragma unroll
            for (int ni = 0; ni < 4; ++ni)
                acc[mi][ni] = __builtin_amdgcn_mfma_f32_16x16x32_bf16(
                    af[mi], bfr[ni], acc[mi][ni], 0, 0, 0);

        __syncthreads();
    }

    float bb[4];
    #pragma unroll
    for (int ni = 0; ni < 4; ++ni)
        bb[ni] = bo[bn + wn * 64 + ni * 16 + lm];

    #pragma unroll
    for (int mi = 0; mi < 2; ++mi)
        #pragma unroll
        for (int r = 0; r < 4; ++r) {
            const int row = bm + wm * 32 + mi * 16 + quad * 4 + r;
            #pragma unroll
            for (int ni = 0; ni < 4; ++ni) {
                const int col = bn + wn * 64 + ni * 16 + lm;
                out[(size_t)row * D_MODEL + col] = acc[mi][ni][r] + bb[ni];
            }
        }
}

// ---------------------------------------------------------------------------
// MFMA flash attention v3: S^T form, 32x32x16, in-register P transpose
// (permlane32_swap), NO split-S, fused normalization.
//
// Pipeline: K/V staging double-buffered, issue-early / drain-late, one
// barrier per iter:
//     stage(0); for it: { sync(drain cur); stage(it+1 -> buf^1); compute(cur); }
// so the global_load_lds for tile it+1 lands UNDER compute(it).
//
// LDS: KV dbuf = 2 x (Ks 8K + Vs 8K) = 32K; Qs (16K, used once) ALIASES
// buf0; Ls (128 floats) for the l broadcast. Total 33.3 KB -> 4 blocks/CU.
//
// l is complete in-kernel (all 2048 k), so O is normalized here and written
// straight to Cxb (bf16 [B,S,D]).
//
// R4 fix: epilogue batch index must come from bh (b = bh>>4), NOT q>>11 --
// q is per-head [0,2048) so q>>11 was always 0: batch-1 heads overwrote
// batch-0 rows (absmax 3.14 in R3). One-line fix.
// ---------------------------------------------------------------------------
__global__ __launch_bounds__(256, 4) void attn_mfma(
    const unsigned short* __restrict__ Q, const unsigned short* __restrict__ K,
    const unsigned short* __restrict__ V, unsigned short* __restrict__ Cx)
{
    __shared__ __align__(16) unsigned char raw[33280];
    // buf b: Ks at raw + b*16384 ([2][64][32] ushorts), Vs at +8192
    unsigned short (*Qs)[128][32] = (unsigned short (*)[128][32])raw; // aliases buf0
    float* Ls = (float*)(raw + 32768);           // [4][32] per-wave l broadcast

    const int t = threadIdx.x, lane = t & 63, w = t >> 6;
    const int q5 = lane & 31, hi = lane >> 5;
    const int lr = lane >> 2, lcs = STAGE_OFS(lane);
    const int q0 = blockIdx.x * 128, bh = blockIdx.y;
    const int sw = (q5 >> 1) & 3;              // row-swizzle for frag reads
    int sbo[4];
    #pragma unroll
    for (int sb = 0; sb < 4; ++sb) sbo[sb] = (sb ^ sw) * 8;

    const unsigned short* Qh = Q + (size_t)bh * (S_LEN * DHEAD);
    const unsigned short* Kh = K + (size_t)bh * (S_LEN * DHEAD);
    const unsigned short* Vh = V + (size_t)bh * (DHEAD * S_LEN);

    // stage Q tile once: wave w stages rows w*32 .. w*32+31, both d-halves
    #pragma unroll
    for (int i = 0; i < 2; ++i)
        #pragma unroll
        for (int c = 0; c < 2; ++c)
            GLOAD16(Qh + (size_t)(q0 + w * 32 + c * 16 + lr) * DHEAD + i * 32 + lcs,
                    &Qs[i][w * 32 + c * 16][0]);
    __syncthreads();

    // hoist Q B-frags into registers
    short8 qf[4];
    #pragma unroll
    for (int c = 0; c < 4; ++c)
        qf[c] = *(const short8*)&Qs[c >> 1][w * 32 + q5][sbo[(c & 1) * 2 + hi]];
    __syncthreads();                           // Qs dead; buf0 may clobber it

    // stage K/V tile `IT` into buffer BUF (8KB Ks + 8KB Vs)
    #define STAGE_KV(IT, BUF) do {                                            \
        const int kt_ = (IT) * 64;                                            \
        unsigned short* ksb_ = (unsigned short*)(raw + (BUF) * 16384);        \
        unsigned short* vsb_ = ksb_ + 4096;                                   \
        _Pragma("unroll")                                                     \
        for (int i_ = 0; i_ < 2; ++i_) {                                      \
            GLOAD16(Kh + (size_t)(kt_ + w * 16 + lr) * DHEAD + i_ * 32 + lcs, \
                    ksb_ + (i_ * 64 + w * 16) * 32);                          \
            GLOAD16(Vh + (size_t)(w * 16 + lr) * S_LEN + kt_ + i_ * 32 + lcs, \
                    vsb_ + (i_ * 64 + w * 16) * 32);                          \
        }                                                                     \
    } while (0)

    STAGE_KV(0, 0);

    f32x16 acc[2] = {};   // O strip: [d-tile][16 regs], row=q, col=d
    float2 l2a = {0.f, 0.f}, l2b = {0.f, 0.f};

    for (int it = 0; it < 32; ++it) {
        const int cur = it & 1;
        __syncthreads();   // drains vmcnt: buf[cur] ready; prev compute done
        if (it + 1 < 32)
            STAGE_KV(it + 1, cur ^ 1);         // lands under compute(cur)

        const unsigned short* ks = (const unsigned short*)(raw + cur * 16384);
        const unsigned short* vs = ks + 4096;

        // ---- S^T: rows k = mt*32 + C-pattern, col q = q5 ----
        f32x16 sf[2] = {};
        #pragma unroll
        for (int c = 0; c < 4; ++c) {
            #pragma unroll
            for (int mt = 0; mt < 2; ++mt) {
                const short8 kf = *(const short8*)
                    &ks[((c >> 1) * 64 + mt * 32 + q5) * 32 + sbo[(c & 1) * 2 + hi]];
                sf[mt] = __builtin_amdgcn_mfma_f32_32x32x16_bf16(kf, qf[c], sf[mt], 0, 0, 0);
            }
        }

        // ---- PV, fully in-register: per instance c, exp 8 P-values,
        // pack to 4 dwords, 2 permlane32_swap -> exact A-frag; MFMA x2 ----
        #pragma unroll
        for (int c = 0; c < 4; ++c) {
            const int mt = c >> 1, pp = c & 1;
            float p[8];
            #pragma unroll
            for (int e = 0; e < 8; ++e)
                p[e] = __ocml_native_exp2_f32(sf[mt][pp * 8 + e]);
            l2a.x += p[0]; l2a.y += p[1]; l2b.x += p[2]; l2b.y += p[3];
            l2a.x += p[4]; l2a.y += p[5]; l2b.x += p[6]; l2b.y += p[7];
            const unsigned int dA = pk2b(p[0], p[1]);
            const unsigned int dB = pk2b(p[2], p[3]);
            const unsigned int sA = pk2b(p[4], p[5]);
            const unsigned int sB = pk2b(p[6], p[7]);
            const uint2v wA = __builtin_amdgcn_permlane32_swap(dA, sA, false, false);
            const uint2v wB = __builtin_amdgcn_permlane32_swap(dB, sB, false, false);
            uint4v wrds;
            wrds.x = wA.x; wrds.y = wB.x; wrds.z = wA.y; wrds.w = wB.y;
            const short8 pf = __builtin_bit_cast(short8, wrds);
            #pragma unroll
            for (int nt = 0; nt < 2; ++nt) {
                const short8 vf = *(const short8*)
                    &vs[((c >> 1) * 64 + nt * 32 + q5) * 32 + sbo[(c & 1) * 2 + hi]];
                acc[nt] = __builtin_amdgcn_mfma_f32_32x32x16_bf16(pf, vf, acc[nt], 0, 0, 0);
            }
        }
    }
    #undef STAGE_KV

    // ---- epilogue: full l -> normalize in-kernel, write bf16 Cx [B,S,D] ----
    float l_acc = (l2a.x + l2a.y) + (l2b.x + l2b.y);
    l_acc += __shfl_xor(l_acc, 32);            // full 2048-k sum for q-row q5
    if (hi == 0)
        Ls[w * 32 + q5] = l_acc;               // wave-local: lgkm dep, no barrier
    const int b = bh >> 4, h = bh & 15;
    #pragma unroll
    for (int reg = 0; reg < 16; ++reg) {
        const int row = (reg & 3) + 8 * (reg >> 2) + 4 * hi;
        const float inv = 1.f / Ls[w * 32 + row];
        const int q = q0 + w * 32 + row;       // s index within this head
        unsigned short* dst = &Cx[((size_t)(b * S_LEN + q)) * D_MODEL + h * 64];
        dst[q5]      = f2b(acc[0][reg] * inv);
        dst[32 + q5] = f2b(acc[1][reg] * inv);
    }
}

// ---------------------------------------------------------------------------
extern "C" void kernel_launch(void* const* d_in, const int* in_sizes, int n_in,
                              void* d_out, int out_size, void* d_ws, size_t ws_size,
                              hipStream_t stream)
{
    const float* x  = (const float*)d_in[0];
    const float* Wq = (const float*)d_in[1];
    const float* bq = (const float*)d_in[2];
    const float* Wk = (const float*)d_in[3];
    const float* bk = (const float*)d_in[4];
    const float* Wv = (const float*)d_in[5];
    const float* bv = (const float*)d_in[6];
    const float* Wo = (const float*)d_in[7];
    const float* bo = (const float*)d_in[8];
    float* out = (float*)d_out;

    // ws layout (ushort units), 40MB total. Cxb ALIASES xb (xb dead after
    // gemm_qkv; attn writes Cxb, gemm_out reads it).
    unsigned short* base = (unsigned short*)d_ws;
    unsigned short* Wot   = base;                   //  0M .. 1M
    unsigned short* Qb    = base + 1 * MEG;         //  1M .. 5M
    unsigned short* Kb    = base + 5 * MEG;         //  5M .. 9M
    unsigned short* Vt    = base + 9 * MEG;         //  9M ..13M
    unsigned short* xb    = base + 13 * MEG;        // 13M ..17M
    unsigned short* Wqt   = base + 17 * MEG;        // 17M ..18M
    unsigned short* Wkt   = base + 18 * MEG;        // 18M ..19M
    unsigned short* Wvt   = base + 19 * MEG;        // 19M ..20M
    unsigned short* Cxb   = xb;                     // aliases xb

    prep<<<dim3(32, 32, 5), dim3(32, 8), 0, stream>>>(
        x, xb, Wq, Wk, Wv, Wo, Wqt, Wkt, Wvt, Wot);

    gemm_qkv<<<dim3(D_MODEL / 128, M_ROWS / 128, 3), dim3(256), 0, stream>>>(
        xb, Wqt, Wkt, Wvt, bq, bk, bv, Qb, Kb, Vt);

    attn_mfma<<<dim3(S_LEN / 128, BHEADS), dim3(256), 0, stream>>>(
        Qb, Kb, Vt, Cxb);

    gemm_out<<<dim3(D_MODEL / 128, M_ROWS / 64), dim3(256), 0, stream>>>(
        Cxb, Wot, bo, out);
}

// Round 5
// 197.835 us; speedup vs baseline: 1.0349x; 1.0072x over previous
//
#include <hip/hip_runtime.h>
#include <hip/hip_bf16.h>

// B=2, S=2048, D=1024, H=16, DH=64
#define S_LEN   2048
#define D_MODEL 1024
#define NHEAD   16
#define DHEAD   64
#define M_ROWS  4096   // B*S
#define BHEADS  32     // B*H
#define MEG     1048576

typedef __attribute__((ext_vector_type(8)))  short short8;   // 8 bf16 (4 VGPRs)
typedef __attribute__((ext_vector_type(4)))  float f32x4;
typedef __attribute__((ext_vector_type(16))) float f32x16;
typedef __attribute__((ext_vector_type(4)))  unsigned short us4;
typedef __attribute__((ext_vector_type(2)))  unsigned int uint2v;
typedef __attribute__((ext_vector_type(4)))  unsigned int uint4v;

// fast native exp2 (single v_exp_f32) from ROCm device libs
extern "C" __device__ float __ocml_native_exp2_f32(float);

// fp32 -> bf16 round-to-nearest-even
__device__ __forceinline__ unsigned short f2b(float f) {
    unsigned int u = __builtin_bit_cast(unsigned int, f);
    return (unsigned short)((u + 0x7FFFu + ((u >> 16) & 1u)) >> 16);
}

// pack two fp32 -> two bf16 in one dword, RTNE (gfx950 v_cvt_pk_bf16_f32).
// Replaces the 3-op bit-twiddle pack (2 adds + perm) with 1 instruction.
__device__ __forceinline__ unsigned int cvtpk(float lo, float hi) {
    unsigned int r;
    asm("v_cvt_pk_bf16_f32 %0, %1, %2" : "=v"(r) : "v"(lo), "v"(hi));
    return r;
}

__device__ __forceinline__ float b2f(unsigned short b) {
    return __builtin_bit_cast(float, (unsigned int)b << 16);
}

// async global->LDS, 16B per lane; LDS dest = wave-uniform base + lane*16
#define GLOAD16(gp, lp) __builtin_amdgcn_global_load_lds(                     \
        (const __attribute__((address_space(1))) void*)(gp),                  \
        (__attribute__((address_space(3))) void*)(lp), 16, 0, 0)

// Bank swizzle: logical 16B sub-block sb of row r lives at phys sb ^ ((r>>1)&3).
#define STAGE_OFS(lane) ((((lane) & 3) ^ (((lane) >> 3) & 3)) * 8)

// ---------------------------------------------------------------------------
// Fused prep: z<4 -> transpose W z to bf16 Wt[n][k]; z==4 -> convert x to bf16
// ---------------------------------------------------------------------------
__global__ __launch_bounds__(256) void prep(
    const float* __restrict__ x, unsigned short* __restrict__ xb,
    const float* __restrict__ Wq, const float* __restrict__ Wk,
    const float* __restrict__ Wv, const float* __restrict__ Wo,
    unsigned short* __restrict__ Wqt, unsigned short* __restrict__ Wkt,
    unsigned short* __restrict__ Wvt, unsigned short* __restrict__ Wot)
{
    const int z = blockIdx.z;
    const int tx = threadIdx.x, ty = threadIdx.y;     // 32 x 8
    if (z == 4) {
        const int blk = blockIdx.y * 32 + blockIdx.x;     // 0..1023
        const int base = (blk * 256 + ty * 32 + tx) * 4;
        #pragma unroll
        for (int r = 0; r < 4; ++r) {
            const int i = base + r * (M_ROWS * D_MODEL / 4);
            const float4 v = *(const float4*)&x[i];
            us4 o;
            o.x = f2b(v.x); o.y = f2b(v.y); o.z = f2b(v.z); o.w = f2b(v.w);
            *(us4*)&xb[i] = o;
        }
        return;
    }
    __shared__ float tile[32][33];
    const float* W = z == 0 ? Wq : (z == 1 ? Wk : (z == 2 ? Wv : Wo));
    unsigned short* Wt = z == 0 ? Wqt : (z == 1 ? Wkt : (z == 2 ? Wvt : Wot));
    const int n0 = blockIdx.x * 32, k0 = blockIdx.y * 32;
    #pragma unroll
    for (int i = 0; i < 4; ++i)
        tile[ty + i * 8][tx] = W[(size_t)(k0 + ty + i * 8) * D_MODEL + n0 + tx];
    __syncthreads();
    #pragma unroll
    for (int i = 0; i < 4; ++i)
        Wt[(size_t)(n0 + ty + i * 8) * D_MODEL + k0 + tx] = f2b(tile[tx][ty + i * 8]);
}

// ---------------------------------------------------------------------------
// Fused Q/K/V projection GEMM (z = 0/1/2), double-buffered single-barrier.
// ---------------------------------------------------------------------------
__global__ __launch_bounds__(256) void gemm_qkv(
    const unsigned short* __restrict__ xb,
    const unsigned short* __restrict__ Wqt, const unsigned short* __restrict__ Wkt,
    const unsigned short* __restrict__ Wvt,
    const float* __restrict__ bq, const float* __restrict__ bk,
    const float* __restrict__ bv,
    unsigned short* __restrict__ Qb, unsigned short* __restrict__ Kb,
    unsigned short* __restrict__ Vt)
{
    __shared__ unsigned short As[2][128][32];
    __shared__ unsigned short Bs[2][128][32];

    const int z = blockIdx.z;
    const unsigned short* Wt = z == 0 ? Wqt : (z == 1 ? Wkt : Wvt);
    const float* bias = z == 0 ? bq : (z == 1 ? bk : bv);

    const int t = threadIdx.x, lane = t & 63, w = t >> 6;
    const int wm = w >> 1, wn = w & 1;
    const int bm = blockIdx.y * 128, bn = blockIdx.x * 128;
    const int lr = lane >> 2, lc = STAGE_OFS(lane);
    const int lm = lane & 15, quad = lane >> 4;
    const int qo = (quad ^ ((lm >> 1) & 3)) * 8;      // swizzled frag offset

    f32x4 acc[4][4] = {};

    #pragma unroll
    for (int i = 0; i < 2; ++i) {
        const int c = 2 * w + i;
        GLOAD16(xb + (size_t)(bm + c * 16 + lr) * D_MODEL + lc, &As[0][c * 16][0]);
        GLOAD16(Wt + (size_t)(bn + c * 16 + lr) * D_MODEL + lc, &Bs[0][c * 16][0]);
    }
    __syncthreads();

    for (int it = 0; it < 32; ++it) {
        const int cur = it & 1;
        if (it + 1 < 32) {
            const int kt = (it + 1) * 32;
            #pragma unroll
            for (int i = 0; i < 2; ++i) {
                const int c = 2 * w + i;
                GLOAD16(xb + (size_t)(bm + c * 16 + lr) * D_MODEL + kt + lc,
                        &As[cur ^ 1][c * 16][0]);
                GLOAD16(Wt + (size_t)(bn + c * 16 + lr) * D_MODEL + kt + lc,
                        &Bs[cur ^ 1][c * 16][0]);
            }
        }

        short8 af[4], bfr[4];
        #pragma unroll
        for (int mi = 0; mi < 4; ++mi)
            af[mi] = *(const short8*)&As[cur][wm * 64 + mi * 16 + lm][qo];
        #pragma unroll
        for (int ni = 0; ni < 4; ++ni)
            bfr[ni] = *(const short8*)&Bs[cur][wn * 64 + ni * 16 + lm][qo];
        #pragma unroll
        for (int mi = 0; mi < 4; ++mi)
            #pragma unroll
            for (int ni = 0; ni < 4; ++ni)
                acc[mi][ni] = __builtin_amdgcn_mfma_f32_16x16x32_bf16(
                    af[mi], bfr[ni], acc[mi][ni], 0, 0, 0);

        __syncthreads();
    }

    float bb[4];
    #pragma unroll
    for (int ni = 0; ni < 4; ++ni)
        bb[ni] = bias[bn + wn * 64 + ni * 16 + lm];
    const float scale = (z == 0) ? 0.18033688011112042f : 1.0f;  // (1/8)*log2e

    if (z < 2) {
        unsigned short* Out = (z == 0) ? Qb : Kb;
        #pragma unroll
        for (int mi = 0; mi < 4; ++mi)
            #pragma unroll
            for (int r = 0; r < 4; ++r) {
                const int row = bm + wm * 64 + mi * 16 + quad * 4 + r;
                const int b = row >> 11, s = row & 2047;
                #pragma unroll
                for (int ni = 0; ni < 4; ++ni) {
                    const int col = bn + wn * 64 + ni * 16 + lm;
                    const int h = col >> 6, d = col & 63;
                    Out[(((size_t)(b * NHEAD + h)) * S_LEN + s) * DHEAD + d] =
                        f2b((acc[mi][ni][r] + bb[ni]) * scale);
                }
            }
    } else {
        #pragma unroll
        for (int mi = 0; mi < 4; ++mi) {
            const int row0 = bm + wm * 64 + mi * 16 + quad * 4;
            const int b = row0 >> 11, s0 = row0 & 2047;
            #pragma unroll
            for (int ni = 0; ni < 4; ++ni) {
                const int col = bn + wn * 64 + ni * 16 + lm;
                const int h = col >> 6, d = col & 63;
                us4 pk;
                pk.x = f2b(acc[mi][ni][0] + bb[ni]);
                pk.y = f2b(acc[mi][ni][1] + bb[ni]);
                pk.z = f2b(acc[mi][ni][2] + bb[ni]);
                pk.w = f2b(acc[mi][ni][3] + bb[ni]);
                *(us4*)&Vt[(((size_t)(b * NHEAD + h)) * DHEAD + d) * S_LEN + s0] = pk;
            }
        }
    }
}

// ---------------------------------------------------------------------------
// Output projection: 64x128 tile, double-buffered single-barrier K-loop.
// ---------------------------------------------------------------------------
__global__ __launch_bounds__(256) void gemm_out(
    const unsigned short* __restrict__ Ab, const unsigned short* __restrict__ Wot,
    const float* __restrict__ bo, float* __restrict__ out)
{
    __shared__ unsigned short As[2][64][32];
    __shared__ unsigned short Bs[2][128][32];

    const int t = threadIdx.x, lane = t & 63, w = t >> 6;
    const int wm = w & 1, wn = w >> 1;
    const int bm = blockIdx.y * 64, bn = blockIdx.x * 128;
    const int lr = lane >> 2, lc = STAGE_OFS(lane);
    const int lm = lane & 15, quad = lane >> 4;
    const int qo = (quad ^ ((lm >> 1) & 3)) * 8;

    f32x4 acc[2][4] = {};

    GLOAD16(Ab + (size_t)(bm + w * 16 + lr) * D_MODEL + lc, &As[0][w * 16][0]);
    #pragma unroll
    for (int i = 0; i < 2; ++i)
        GLOAD16(Wot + (size_t)(bn + w * 32 + i * 16 + lr) * D_MODEL + lc,
                &Bs[0][w * 32 + i * 16][0]);
    __syncthreads();

    for (int it = 0; it < 32; ++it) {
        const int cur = it & 1;
        if (it + 1 < 32) {
            const int kt = (it + 1) * 32;
            GLOAD16(Ab + (size_t)(bm + w * 16 + lr) * D_MODEL + kt + lc,
                    &As[cur ^ 1][w * 16][0]);
            #pragma unroll
            for (int i = 0; i < 2; ++i)
                GLOAD16(Wot + (size_t)(bn + w * 32 + i * 16 + lr) * D_MODEL + kt + lc,
                        &Bs[cur ^ 1][w * 32 + i * 16][0]);
        }

        short8 af[2], bfr[4];
        #pragma unroll
        for (int mi = 0; mi < 2; ++mi)
            af[mi] = *(const short8*)&As[cur][wm * 32 + mi * 16 + lm][qo];
        #pragma unroll
        for (int ni = 0; ni < 4; ++ni)
            bfr[ni] = *(const short8*)&Bs[cur][wn * 64 + ni * 16 + lm][qo];
        #pragma unroll
        for (int mi = 0; mi < 2; ++mi)
            #pragma unroll
            for (int ni = 0; ni < 4; ++ni)
                acc[mi][ni] = __builtin_amdgcn_mfma_f32_16x16x32_bf16(
                    af[mi], bfr[ni], acc[mi][ni], 0, 0, 0);

        __syncthreads();
    }

    float bb[4];
    #pragma unroll
    for (int ni = 0; ni < 4; ++ni)
        bb[ni] = bo[bn + wn * 64 + ni * 16 + lm];

    #pragma unroll
    for (int mi = 0; mi < 2; ++mi)
        #pragma unroll
        for (int r = 0; r < 4; ++r) {
            const int row = bm + wm * 32 + mi * 16 + quad * 4 + r;
            #pragma unroll
            for (int ni = 0; ni < 4; ++ni) {
                const int col = bn + wn * 64 + ni * 16 + lm;
                out[(size_t)row * D_MODEL + col] = acc[mi][ni][r] + bb[ni];
            }
        }
}

// ---------------------------------------------------------------------------
// MFMA flash attention v4: S^T form, 32x32x16, in-register P transpose
// (permlane32_swap), NO split-S, fused normalization, issue-early KV dbuf.
//
// R5 changes:
// 1. T1 XCD-chunked block swizzle. Grid (16,32) x-fastest meant a head's 16
//    q-blocks were consecutive dispatch ids -> round-robined over all 8 XCDs
//    -> each head's 512KB K/V fetched into ~8 XCD-L2s (FETCH 70MB vs ~24
//    ideal, and exposed ~900cy HBM latency at only 2 waves/SIMD).
//    swz = (id&7)*64 + id>>3 (bijective, 512%8==0): 4 whole heads per XCD,
//    2MB K/V resident in 4MB L2 -> staging becomes L2-hit.
// 2. P-pack via v_cvt_pk_bf16_f32 (1 instr, RTNE) instead of 3-op bit pack:
//    48 -> 16 VALU ops per iter on the softmax path.
// ---------------------------------------------------------------------------
__global__ __launch_bounds__(256, 4) void attn_mfma(
    const unsigned short* __restrict__ Q, const unsigned short* __restrict__ K,
    const unsigned short* __restrict__ V, unsigned short* __restrict__ Cx)
{
    __shared__ __align__(16) unsigned char raw[33280];
    // buf b: Ks at raw + b*16384 ([2][64][32] ushorts), Vs at +8192
    unsigned short (*Qs)[128][32] = (unsigned short (*)[128][32])raw; // aliases buf0
    float* Ls = (float*)(raw + 32768);           // [4][32] per-wave l broadcast

    const int t = threadIdx.x, lane = t & 63, w = t >> 6;
    const int q5 = lane & 31, hi = lane >> 5;
    const int lr = lane >> 2, lcs = STAGE_OFS(lane);
    // T1: XCD-chunked swizzle of the 512-block grid (see header comment)
    const int id  = blockIdx.y * 16 + blockIdx.x;   // dispatch-linear id
    const int swz = (id & 7) * 64 + (id >> 3);      // bijective remap
    const int q0 = (swz & 15) * 128, bh = swz >> 4;
    const int sw = (q5 >> 1) & 3;              // row-swizzle for frag reads
    int sbo[4];
    #pragma unroll
    for (int sb = 0; sb < 4; ++sb) sbo[sb] = (sb ^ sw) * 8;

    const unsigned short* Qh = Q + (size_t)bh * (S_LEN * DHEAD);
    const unsigned short* Kh = K + (size_t)bh * (S_LEN * DHEAD);
    const unsigned short* Vh = V + (size_t)bh * (DHEAD * S_LEN);

    // stage Q tile once: wave w stages rows w*32 .. w*32+31, both d-halves
    #pragma unroll
    for (int i = 0; i < 2; ++i)
        #pragma unroll
        for (int c = 0; c < 2; ++c)
            GLOAD16(Qh + (size_t)(q0 + w * 32 + c * 16 + lr) * DHEAD + i * 32 + lcs,
                    &Qs[i][w * 32 + c * 16][0]);
    __syncthreads();

    // hoist Q B-frags into registers
    short8 qf[4];
    #pragma unroll
    for (int c = 0; c < 4; ++c)
        qf[c] = *(const short8*)&Qs[c >> 1][w * 32 + q5][sbo[(c & 1) * 2 + hi]];
    __syncthreads();                           // Qs dead; buf0 may clobber it

    // stage K/V tile `IT` into buffer BUF (8KB Ks + 8KB Vs)
    #define STAGE_KV(IT, BUF) do {                                            \
        const int kt_ = (IT) * 64;                                            \
        unsigned short* ksb_ = (unsigned short*)(raw + (BUF) * 16384);        \
        unsigned short* vsb_ = ksb_ + 4096;                                   \
        _Pragma("unroll")                                                     \
        for (int i_ = 0; i_ < 2; ++i_) {                                      \
            GLOAD16(Kh + (size_t)(kt_ + w * 16 + lr) * DHEAD + i_ * 32 + lcs, \
                    ksb_ + (i_ * 64 + w * 16) * 32);                          \
            GLOAD16(Vh + (size_t)(w * 16 + lr) * S_LEN + kt_ + i_ * 32 + lcs, \
                    vsb_ + (i_ * 64 + w * 16) * 32);                          \
        }                                                                     \
    } while (0)

    STAGE_KV(0, 0);

    f32x16 acc[2] = {};   // O strip: [d-tile][16 regs], row=q, col=d
    float2 l2a = {0.f, 0.f}, l2b = {0.f, 0.f};

    for (int it = 0; it < 32; ++it) {
        const int cur = it & 1;
        __syncthreads();   // drains vmcnt: buf[cur] ready; prev compute done
        if (it + 1 < 32)
            STAGE_KV(it + 1, cur ^ 1);         // lands under compute(cur)

        const unsigned short* ks = (const unsigned short*)(raw + cur * 16384);
        const unsigned short* vs = ks + 4096;

        // ---- S^T: rows k = mt*32 + C-pattern, col q = q5 ----
        f32x16 sf[2] = {};
        #pragma unroll
        for (int c = 0; c < 4; ++c) {
            #pragma unroll
            for (int mt = 0; mt < 2; ++mt) {
                const short8 kf = *(const short8*)
                    &ks[((c >> 1) * 64 + mt * 32 + q5) * 32 + sbo[(c & 1) * 2 + hi]];
                sf[mt] = __builtin_amdgcn_mfma_f32_32x32x16_bf16(kf, qf[c], sf[mt], 0, 0, 0);
            }
        }

        // ---- PV, fully in-register: per instance c, exp 8 P-values,
        // cvt_pk to 4 dwords, 2 permlane32_swap -> exact A-frag; MFMA x2 ----
        #pragma unroll
        for (int c = 0; c < 4; ++c) {
            const int mt = c >> 1, pp = c & 1;
            float p[8];
            #pragma unroll
            for (int e = 0; e < 8; ++e)
                p[e] = __ocml_native_exp2_f32(sf[mt][pp * 8 + e]);
            l2a.x += p[0]; l2a.y += p[1]; l2b.x += p[2]; l2b.y += p[3];
            l2a.x += p[4]; l2a.y += p[5]; l2b.x += p[6]; l2b.y += p[7];
            const unsigned int dA = cvtpk(p[0], p[1]);
            const unsigned int dB = cvtpk(p[2], p[3]);
            const unsigned int sA = cvtpk(p[4], p[5]);
            const unsigned int sB = cvtpk(p[6], p[7]);
            const uint2v wA = __builtin_amdgcn_permlane32_swap(dA, sA, false, false);
            const uint2v wB = __builtin_amdgcn_permlane32_swap(dB, sB, false, false);
            uint4v wrds;
            wrds.x = wA.x; wrds.y = wB.x; wrds.z = wA.y; wrds.w = wB.y;
            const short8 pf = __builtin_bit_cast(short8, wrds);
            #pragma unroll
            for (int nt = 0; nt < 2; ++nt) {
                const short8 vf = *(const short8*)
                    &vs[((c >> 1) * 64 + nt * 32 + q5) * 32 + sbo[(c & 1) * 2 + hi]];
                acc[nt] = __builtin_amdgcn_mfma_f32_32x32x16_bf16(pf, vf, acc[nt], 0, 0, 0);
            }
        }
    }
    #undef STAGE_KV

    // ---- epilogue: full l -> normalize in-kernel, write bf16 Cx [B,S,D] ----
    float l_acc = (l2a.x + l2a.y) + (l2b.x + l2b.y);
    l_acc += __shfl_xor(l_acc, 32);            // full 2048-k sum for q-row q5
    if (hi == 0)
        Ls[w * 32 + q5] = l_acc;               // wave-local: lgkm dep, no barrier
    const int b = bh >> 4, h = bh & 15;
    #pragma unroll
    for (int reg = 0; reg < 16; ++reg) {
        const int row = (reg & 3) + 8 * (reg >> 2) + 4 * hi;
        const float inv = 1.f / Ls[w * 32 + row];
        const int q = q0 + w * 32 + row;       // s index within this head
        unsigned short* dst = &Cx[((size_t)(b * S_LEN + q)) * D_MODEL + h * 64];
        dst[q5]      = f2b(acc[0][reg] * inv);
        dst[32 + q5] = f2b(acc[1][reg] * inv);
    }
}

// ---------------------------------------------------------------------------
extern "C" void kernel_launch(void* const* d_in, const int* in_sizes, int n_in,
                              void* d_out, int out_size, void* d_ws, size_t ws_size,
                              hipStream_t stream)
{
    const float* x  = (const float*)d_in[0];
    const float* Wq = (const float*)d_in[1];
    const float* bq = (const float*)d_in[2];
    const float* Wk = (const float*)d_in[3];
    const float* bk = (const float*)d_in[4];
    const float* Wv = (const float*)d_in[5];
    const float* bv = (const float*)d_in[6];
    const float* Wo = (const float*)d_in[7];
    const float* bo = (const float*)d_in[8];
    float* out = (float*)d_out;

    // ws layout (ushort units), 40MB total. Cxb ALIASES xb (xb dead after
    // gemm_qkv; attn writes Cxb, gemm_out reads it).
    unsigned short* base = (unsigned short*)d_ws;
    unsigned short* Wot   = base;                   //  0M .. 1M
    unsigned short* Qb    = base + 1 * MEG;         //  1M .. 5M
    unsigned short* Kb    = base + 5 * MEG;         //  5M .. 9M
    unsigned short* Vt    = base + 9 * MEG;         //  9M ..13M
    unsigned short* xb    = base + 13 * MEG;        // 13M ..17M
    unsigned short* Wqt   = base + 17 * MEG;        // 17M ..18M
    unsigned short* Wkt   = base + 18 * MEG;        // 18M ..19M
    unsigned short* Wvt   = base + 19 * MEG;        // 19M ..20M
    unsigned short* Cxb   = xb;                     // aliases xb

    prep<<<dim3(32, 32, 5), dim3(32, 8), 0, stream>>>(
        x, xb, Wq, Wk, Wv, Wo, Wqt, Wkt, Wvt, Wot);

    gemm_qkv<<<dim3(D_MODEL / 128, M_ROWS / 128, 3), dim3(256), 0, stream>>>(
        xb, Wqt, Wkt, Wvt, bq, bk, bv, Qb, Kb, Vt);

    attn_mfma<<<dim3(S_LEN / 128, BHEADS), dim3(256), 0, stream>>>(
        Qb, Kb, Vt, Cxb);

    gemm_out<<<dim3(D_MODEL / 128, M_ROWS / 64), dim3(256), 0, stream>>>(
        Cxb, Wot, bo, out);
}

// Round 6
// 193.491 us; speedup vs baseline: 1.0581x; 1.0225x over previous
//
#include <hip/hip_runtime.h>
#include <hip/hip_bf16.h>

// B=2, S=2048, D=1024, H=16, DH=64
#define S_LEN   2048
#define D_MODEL 1024
#define NHEAD   16
#define DHEAD   64
#define M_ROWS  4096   // B*S
#define BHEADS  32     // B*H
#define MEG     1048576

typedef __attribute__((ext_vector_type(8)))  short short8;   // 8 bf16 (4 VGPRs)
typedef __attribute__((ext_vector_type(4)))  float f32x4;
typedef __attribute__((ext_vector_type(16))) float f32x16;
typedef __attribute__((ext_vector_type(4)))  unsigned short us4;
typedef __attribute__((ext_vector_type(2)))  unsigned int uint2v;
typedef __attribute__((ext_vector_type(4)))  unsigned int uint4v;

// fast native exp2 (single v_exp_f32) from ROCm device libs
extern "C" __device__ float __ocml_native_exp2_f32(float);

// fp32 -> bf16 round-to-nearest-even
__device__ __forceinline__ unsigned short f2b(float f) {
    unsigned int u = __builtin_bit_cast(unsigned int, f);
    return (unsigned short)((u + 0x7FFFu + ((u >> 16) & 1u)) >> 16);
}

// pack two fp32 -> two bf16 in one dword, RTNE (gfx950 v_cvt_pk_bf16_f32).
__device__ __forceinline__ unsigned int cvtpk(float lo, float hi) {
    unsigned int r;
    asm("v_cvt_pk_bf16_f32 %0, %1, %2" : "=v"(r) : "v"(lo), "v"(hi));
    return r;
}

__device__ __forceinline__ float b2f(unsigned short b) {
    return __builtin_bit_cast(float, (unsigned int)b << 16);
}

// async global->LDS, 16B per lane; LDS dest = wave-uniform base + lane*16
#define GLOAD16(gp, lp) __builtin_amdgcn_global_load_lds(                     \
        (const __attribute__((address_space(1))) void*)(gp),                  \
        (__attribute__((address_space(3))) void*)(lp), 16, 0, 0)

// Bank swizzle: logical 16B sub-block sb of row r lives at phys sb ^ ((r>>1)&3).
#define STAGE_OFS(lane) ((((lane) & 3) ^ (((lane) >> 3) & 3)) * 8)

#define ZERO16(v) do { _Pragma("unroll")                                      \
    for (int z_ = 0; z_ < 16; ++z_) (v)[z_] = 0.f; } while (0)

// ---------------------------------------------------------------------------
// Fused prep: z<4 -> transpose W z to bf16 Wt[n][k]; z==4 -> convert x to bf16
// ---------------------------------------------------------------------------
__global__ __launch_bounds__(256) void prep(
    const float* __restrict__ x, unsigned short* __restrict__ xb,
    const float* __restrict__ Wq, const float* __restrict__ Wk,
    const float* __restrict__ Wv, const float* __restrict__ Wo,
    unsigned short* __restrict__ Wqt, unsigned short* __restrict__ Wkt,
    unsigned short* __restrict__ Wvt, unsigned short* __restrict__ Wot)
{
    const int z = blockIdx.z;
    const int tx = threadIdx.x, ty = threadIdx.y;     // 32 x 8
    if (z == 4) {
        const int blk = blockIdx.y * 32 + blockIdx.x;     // 0..1023
        const int base = (blk * 256 + ty * 32 + tx) * 4;
        #pragma unroll
        for (int r = 0; r < 4; ++r) {
            const int i = base + r * (M_ROWS * D_MODEL / 4);
            const float4 v = *(const float4*)&x[i];
            us4 o;
            o.x = f2b(v.x); o.y = f2b(v.y); o.z = f2b(v.z); o.w = f2b(v.w);
            *(us4*)&xb[i] = o;
        }
        return;
    }
    __shared__ float tile[32][33];
    const float* W = z == 0 ? Wq : (z == 1 ? Wk : (z == 2 ? Wv : Wo));
    unsigned short* Wt = z == 0 ? Wqt : (z == 1 ? Wkt : (z == 2 ? Wvt : Wot));
    const int n0 = blockIdx.x * 32, k0 = blockIdx.y * 32;
    #pragma unroll
    for (int i = 0; i < 4; ++i)
        tile[ty + i * 8][tx] = W[(size_t)(k0 + ty + i * 8) * D_MODEL + n0 + tx];
    __syncthreads();
    #pragma unroll
    for (int i = 0; i < 4; ++i)
        Wt[(size_t)(n0 + ty + i * 8) * D_MODEL + k0 + tx] = f2b(tile[tx][ty + i * 8]);
}

// ---------------------------------------------------------------------------
// Fused Q/K/V projection GEMM (z = 0/1/2), double-buffered single-barrier.
// ---------------------------------------------------------------------------
__global__ __launch_bounds__(256) void gemm_qkv(
    const unsigned short* __restrict__ xb,
    const unsigned short* __restrict__ Wqt, const unsigned short* __restrict__ Wkt,
    const unsigned short* __restrict__ Wvt,
    const float* __restrict__ bq, const float* __restrict__ bk,
    const float* __restrict__ bv,
    unsigned short* __restrict__ Qb, unsigned short* __restrict__ Kb,
    unsigned short* __restrict__ Vt)
{
    __shared__ unsigned short As[2][128][32];
    __shared__ unsigned short Bs[2][128][32];

    const int z = blockIdx.z;
    const unsigned short* Wt = z == 0 ? Wqt : (z == 1 ? Wkt : Wvt);
    const float* bias = z == 0 ? bq : (z == 1 ? bk : bv);

    const int t = threadIdx.x, lane = t & 63, w = t >> 6;
    const int wm = w >> 1, wn = w & 1;
    const int bm = blockIdx.y * 128, bn = blockIdx.x * 128;
    const int lr = lane >> 2, lc = STAGE_OFS(lane);
    const int lm = lane & 15, quad = lane >> 4;
    const int qo = (quad ^ ((lm >> 1) & 3)) * 8;      // swizzled frag offset

    f32x4 acc[4][4] = {};

    #pragma unroll
    for (int i = 0; i < 2; ++i) {
        const int c = 2 * w + i;
        GLOAD16(xb + (size_t)(bm + c * 16 + lr) * D_MODEL + lc, &As[0][c * 16][0]);
        GLOAD16(Wt + (size_t)(bn + c * 16 + lr) * D_MODEL + lc, &Bs[0][c * 16][0]);
    }
    __syncthreads();

    for (int it = 0; it < 32; ++it) {
        const int cur = it & 1;
        if (it + 1 < 32) {
            const int kt = (it + 1) * 32;
            #pragma unroll
            for (int i = 0; i < 2; ++i) {
                const int c = 2 * w + i;
                GLOAD16(xb + (size_t)(bm + c * 16 + lr) * D_MODEL + kt + lc,
                        &As[cur ^ 1][c * 16][0]);
                GLOAD16(Wt + (size_t)(bn + c * 16 + lr) * D_MODEL + kt + lc,
                        &Bs[cur ^ 1][c * 16][0]);
            }
        }

        short8 af[4], bfr[4];
        #pragma unroll
        for (int mi = 0; mi < 4; ++mi)
            af[mi] = *(const short8*)&As[cur][wm * 64 + mi * 16 + lm][qo];
        #pragma unroll
        for (int ni = 0; ni < 4; ++ni)
            bfr[ni] = *(const short8*)&Bs[cur][wn * 64 + ni * 16 + lm][qo];
        #pragma unroll
        for (int mi = 0; mi < 4; ++mi)
            #pragma unroll
            for (int ni = 0; ni < 4; ++ni)
                acc[mi][ni] = __builtin_amdgcn_mfma_f32_16x16x32_bf16(
                    af[mi], bfr[ni], acc[mi][ni], 0, 0, 0);

        __syncthreads();
    }

    float bb[4];
    #pragma unroll
    for (int ni = 0; ni < 4; ++ni)
        bb[ni] = bias[bn + wn * 64 + ni * 16 + lm];
    const float scale = (z == 0) ? 0.18033688011112042f : 1.0f;  // (1/8)*log2e

    if (z < 2) {
        unsigned short* Out = (z == 0) ? Qb : Kb;
        #pragma unroll
        for (int mi = 0; mi < 4; ++mi)
            #pragma unroll
            for (int r = 0; r < 4; ++r) {
                const int row = bm + wm * 64 + mi * 16 + quad * 4 + r;
                const int b = row >> 11, s = row & 2047;
                #pragma unroll
                for (int ni = 0; ni < 4; ++ni) {
                    const int col = bn + wn * 64 + ni * 16 + lm;
                    const int h = col >> 6, d = col & 63;
                    Out[(((size_t)(b * NHEAD + h)) * S_LEN + s) * DHEAD + d] =
                        f2b((acc[mi][ni][r] + bb[ni]) * scale);
                }
            }
    } else {
        #pragma unroll
        for (int mi = 0; mi < 4; ++mi) {
            const int row0 = bm + wm * 64 + mi * 16 + quad * 4;
            const int b = row0 >> 11, s0 = row0 & 2047;
            #pragma unroll
            for (int ni = 0; ni < 4; ++ni) {
                const int col = bn + wn * 64 + ni * 16 + lm;
                const int h = col >> 6, d = col & 63;
                us4 pk;
                pk.x = f2b(acc[mi][ni][0] + bb[ni]);
                pk.y = f2b(acc[mi][ni][1] + bb[ni]);
                pk.z = f2b(acc[mi][ni][2] + bb[ni]);
                pk.w = f2b(acc[mi][ni][3] + bb[ni]);
                *(us4*)&Vt[(((size_t)(b * NHEAD + h)) * DHEAD + d) * S_LEN + s0] = pk;
            }
        }
    }
}

// ---------------------------------------------------------------------------
// Output projection: 64x128 tile, double-buffered single-barrier K-loop.
// ---------------------------------------------------------------------------
__global__ __launch_bounds__(256) void gemm_out(
    const unsigned short* __restrict__ Ab, const unsigned short* __restrict__ Wot,
    const float* __restrict__ bo, float* __restrict__ out)
{
    __shared__ unsigned short As[2][64][32];
    __shared__ unsigned short Bs[2][128][32];

    const int t = threadIdx.x, lane = t & 63, w = t >> 6;
    const int wm = w & 1, wn = w >> 1;
    const int bm = blockIdx.y * 64, bn = blockIdx.x * 128;
    const int lr = lane >> 2, lc = STAGE_OFS(lane);
    const int lm = lane & 15, quad = lane >> 4;
    const int qo = (quad ^ ((lm >> 1) & 3)) * 8;

    f32x4 acc[2][4] = {};

    GLOAD16(Ab + (size_t)(bm + w * 16 + lr) * D_MODEL + lc, &As[0][w * 16][0]);
    #pragma unroll
    for (int i = 0; i < 2; ++i)
        GLOAD16(Wot + (size_t)(bn + w * 32 + i * 16 + lr) * D_MODEL + lc,
                &Bs[0][w * 32 + i * 16][0]);
    __syncthreads();

    for (int it = 0; it < 32; ++it) {
        const int cur = it & 1;
        if (it + 1 < 32) {
            const int kt = (it + 1) * 32;
            GLOAD16(Ab + (size_t)(bm + w * 16 + lr) * D_MODEL + kt + lc,
                    &As[cur ^ 1][w * 16][0]);
            #pragma unroll
            for (int i = 0; i < 2; ++i)
                GLOAD16(Wot + (size_t)(bn + w * 32 + i * 16 + lr) * D_MODEL + kt + lc,
                        &Bs[cur ^ 1][w * 32 + i * 16][0]);
        }

        short8 af[2], bfr[4];
        #pragma unroll
        for (int mi = 0; mi < 2; ++mi)
            af[mi] = *(const short8*)&As[cur][wm * 32 + mi * 16 + lm][qo];
        #pragma unroll
        for (int ni = 0; ni < 4; ++ni)
            bfr[ni] = *(const short8*)&Bs[cur][wn * 64 + ni * 16 + lm][qo];
        #pragma unroll
        for (int mi = 0; mi < 2; ++mi)
            #pragma unroll
            for (int ni = 0; ni < 4; ++ni)
                acc[mi][ni] = __builtin_amdgcn_mfma_f32_16x16x32_bf16(
                    af[mi], bfr[ni], acc[mi][ni], 0, 0, 0);

        __syncthreads();
    }

    float bb[4];
    #pragma unroll
    for (int ni = 0; ni < 4; ++ni)
        bb[ni] = bo[bn + wn * 64 + ni * 16 + lm];

    #pragma unroll
    for (int mi = 0; mi < 2; ++mi)
        #pragma unroll
        for (int r = 0; r < 4; ++r) {
            const int row = bm + wm * 32 + mi * 16 + quad * 4 + r;
            #pragma unroll
            for (int ni = 0; ni < 4; ++ni) {
                const int col = bn + wn * 64 + ni * 16 + lm;
                out[(size_t)row * D_MODEL + col] = acc[mi][ni][r] + bb[ni];
            }
        }
}

// ---------------------------------------------------------------------------
// MFMA flash attention v5: QK one-tile-ahead software pipeline.
//
// R6 changes (attacks the dependency-serialization shown by R5 counters:
// MfmaUtil 29 / VALUBusy 38 / occupancy 16%, HBM 7% -> stall-bound):
// 1. T15-style pipeline: each barrier region computes exp/pack/PV(it) AND
//    QK(it+1) -- mutually independent, so the wave's VALU (exp) overlaps
//    the matrix pipe (QK-next) instead of serializing QK->exp->PV.
//    Requires TRIPLE-buffered KV (stage target must avoid the two live
//    tiles): LDS = 3 x 16K = 48K, grid-limited occupancy unchanged.
//    Staging stays depth-1 (issue at region top, drained by next region's
//    __syncthreads) -- no counted-vmcnt hazard.
//    sf double-state via manual 2x unroll (named sfA/sfB, rule #20).
// 2. l-sum via MFMA: acc_l = mfma(pf, ones, acc_l). Deletes 32 VALU adds
//    + shfl_xor + the Ls LDS broadcast; each lane's acc_l[reg] is l for
//    exactly its output row (same C-layout as acc). l now sums the same
//    bf16 P as the numerator (RTNE, unbiased).
// 3. __launch_bounds__(256,2): matches real 2 blocks/CU, relaxes regalloc.
// ---------------------------------------------------------------------------
__global__ __launch_bounds__(256, 2) void attn_mfma(
    const unsigned short* __restrict__ Q, const unsigned short* __restrict__ K,
    const unsigned short* __restrict__ V, unsigned short* __restrict__ Cx)
{
    __shared__ __align__(16) unsigned char raw[49152];
    // buf b (b=0..2): Ks at raw + b*16384 ([2][64][32] ushorts), Vs at +8192
    unsigned short (*Qs)[128][32] = (unsigned short (*)[128][32])raw; // = buf0

    const int t = threadIdx.x, lane = t & 63, w = t >> 6;
    const int q5 = lane & 31, hi = lane >> 5;
    const int lr = lane >> 2, lcs = STAGE_OFS(lane);
    // T1: XCD-chunked swizzle of the 512-block grid
    const int id  = blockIdx.y * 16 + blockIdx.x;   // dispatch-linear id
    const int swz = (id & 7) * 64 + (id >> 3);      // bijective remap
    const int q0 = (swz & 15) * 128, bh = swz >> 4;
    const int sw = (q5 >> 1) & 3;              // row-swizzle for frag reads
    int sbo[4];
    #pragma unroll
    for (int sb = 0; sb < 4; ++sb) sbo[sb] = (sb ^ sw) * 8;

    const unsigned short* Qh = Q + (size_t)bh * (S_LEN * DHEAD);
    const unsigned short* Kh = K + (size_t)bh * (S_LEN * DHEAD);
    const unsigned short* Vh = V + (size_t)bh * (DHEAD * S_LEN);

    // stage Q tile once into buf0 alias: wave w stages rows w*32..w*32+31
    #pragma unroll
    for (int i = 0; i < 2; ++i)
        #pragma unroll
        for (int c = 0; c < 2; ++c)
            GLOAD16(Qh + (size_t)(q0 + w * 32 + c * 16 + lr) * DHEAD + i * 32 + lcs,
                    &Qs[i][w * 32 + c * 16][0]);
    __syncthreads();

    // hoist Q B-frags into registers
    short8 qf[4];
    #pragma unroll
    for (int c = 0; c < 4; ++c)
        qf[c] = *(const short8*)&Qs[c >> 1][w * 32 + q5][sbo[(c & 1) * 2 + hi]];
    __syncthreads();                           // Qs dead; buf0 reusable

    // all-ones B-frag (bf16 1.0 = 0x3F80) for the l-sum MFMA
    short8 onesf;
    #pragma unroll
    for (int j = 0; j < 8; ++j) onesf[j] = (short)0x3F80;

    // stage K/V tile `IT` into buffer BUF (8KB Ks + 8KB Vs)
    #define STAGE_KV(IT, BUF) do {                                            \
        const int kt_ = (IT) * 64;                                            \
        unsigned short* ksb_ = (unsigned short*)(raw + (BUF) * 16384);        \
        unsigned short* vsb_ = ksb_ + 4096;                                   \
        _Pragma("unroll")                                                     \
        for (int i_ = 0; i_ < 2; ++i_) {                                      \
            GLOAD16(Kh + (size_t)(kt_ + w * 16 + lr) * DHEAD + i_ * 32 + lcs, \
                    ksb_ + (i_ * 64 + w * 16) * 32);                          \
            GLOAD16(Vh + (size_t)(w * 16 + lr) * S_LEN + kt_ + i_ * 32 + lcs, \
                    vsb_ + (i_ * 64 + w * 16) * 32);                          \
        }                                                                     \
    } while (0)

    // QK chain for tile IT from its buffer into SF (must be pre-zeroed)
    #define QK_CHAIN(IT, SF) do {                                             \
        const unsigned short* kn_ = (const unsigned short*)                   \
            (raw + ((IT) % 3) * 16384);                                       \
        _Pragma("unroll")                                                     \
        for (int c_ = 0; c_ < 4; ++c_) {                                      \
            _Pragma("unroll")                                                 \
            for (int mt_ = 0; mt_ < 2; ++mt_) {                               \
                const short8 kf_ = *(const short8*)                           \
                    &kn_[((c_ >> 1) * 64 + mt_ * 32 + q5) * 32                \
                         + sbo[(c_ & 1) * 2 + hi]];                           \
                SF[mt_] = __builtin_amdgcn_mfma_f32_32x32x16_bf16(            \
                    kf_, qf[c_], SF[mt_], 0, 0, 0);                           \
            }                                                                 \
        }                                                                     \
    } while (0)

    f32x16 acc[2];     // O strip: [d-tile][16 regs], row=q, col=d
    f32x16 acc_l;      // l (row-sum) via P x ones; same row layout as acc
    ZERO16(acc[0]); ZERO16(acc[1]); ZERO16(acc_l);
    f32x16 sfA[2], sfB[2];

    // prologue: KV(0) resident; sfA = S(0); KV(1) in flight
    STAGE_KV(0, 0);
    __syncthreads();
    ZERO16(sfA[0]); ZERO16(sfA[1]);
    QK_CHAIN(0, sfA);
    STAGE_KV(1, 1);

    // Region R(it): barrier (drains stage(it+1)); issue stage(it+2);
    // QK(it+1) -> SFN; exp/pack/PV/l(it) from SFC.  All between one pair
    // of barriers -> MFMA(QK-next) overlaps VALU(exp) intra-wave.
    #define REGION(IT, SFC, SFN, DOQK) do {                                   \
        __syncthreads();                                                      \
        if ((IT) + 2 < 32) STAGE_KV((IT) + 2, ((IT) + 2) % 3);                \
        if (DOQK) {                                                           \
            ZERO16(SFN[0]); ZERO16(SFN[1]);                                   \
            QK_CHAIN((IT) + 1, SFN);                                          \
        }                                                                     \
        const unsigned short* vs_ = (const unsigned short*)                   \
            (raw + ((IT) % 3) * 16384) + 4096;                                \
        _Pragma("unroll")                                                     \
        for (int c = 0; c < 4; ++c) {                                         \
            const int mt = c >> 1, pp = c & 1;                                \
            float p[8];                                                       \
            _Pragma("unroll")                                                 \
            for (int e = 0; e < 8; ++e)                                       \
                p[e] = __ocml_native_exp2_f32(SFC[mt][pp * 8 + e]);           \
            const unsigned int dA = cvtpk(p[0], p[1]);                        \
            const unsigned int dB = cvtpk(p[2], p[3]);                        \
            const unsigned int sA = cvtpk(p[4], p[5]);                        \
            const unsigned int sB = cvtpk(p[6], p[7]);                        \
            const uint2v wA = __builtin_amdgcn_permlane32_swap(dA, sA, false, false); \
            const uint2v wB = __builtin_amdgcn_permlane32_swap(dB, sB, false, false); \
            uint4v wrds;                                                      \
            wrds.x = wA.x; wrds.y = wB.x; wrds.z = wA.y; wrds.w = wB.y;       \
            const short8 pf = __builtin_bit_cast(short8, wrds);               \
            acc_l = __builtin_amdgcn_mfma_f32_32x32x16_bf16(                  \
                pf, onesf, acc_l, 0, 0, 0);                                   \
            _Pragma("unroll")                                                 \
            for (int nt = 0; nt < 2; ++nt) {                                  \
                const short8 vf = *(const short8*)                            \
                    &vs_[((c >> 1) * 64 + nt * 32 + q5) * 32                  \
                         + sbo[(c & 1) * 2 + hi]];                            \
                acc[nt] = __builtin_amdgcn_mfma_f32_32x32x16_bf16(            \
                    pf, vf, acc[nt], 0, 0, 0);                                \
            }                                                                 \
        }                                                                     \
    } while (0)

    for (int itp = 0; itp < 16; ++itp) {
        const int it0 = itp * 2;
        REGION(it0, sfA, sfB, true);
        REGION(it0 + 1, sfB, sfA, (it0 + 2) < 32);
    }
    #undef REGION
    #undef QK_CHAIN
    #undef STAGE_KV

    // ---- epilogue: l is complete per-lane in acc_l; normalize + write ----
    const int b = bh >> 4, h = bh & 15;
    #pragma unroll
    for (int reg = 0; reg < 16; ++reg) {
        const int row = (reg & 3) + 8 * (reg >> 2) + 4 * hi;
        const float inv = 1.f / acc_l[reg];
        const int q = q0 + w * 32 + row;       // s index within this head
        unsigned short* dst = &Cx[((size_t)(b * S_LEN + q)) * D_MODEL + h * 64];
        dst[q5]      = f2b(acc[0][reg] * inv);
        dst[32 + q5] = f2b(acc[1][reg] * inv);
    }
}

// ---------------------------------------------------------------------------
extern "C" void kernel_launch(void* const* d_in, const int* in_sizes, int n_in,
                              void* d_out, int out_size, void* d_ws, size_t ws_size,
                              hipStream_t stream)
{
    const float* x  = (const float*)d_in[0];
    const float* Wq = (const float*)d_in[1];
    const float* bq = (const float*)d_in[2];
    const float* Wk = (const float*)d_in[3];
    const float* bk = (const float*)d_in[4];
    const float* Wv = (const float*)d_in[5];
    const float* bv = (const float*)d_in[6];
    const float* Wo = (const float*)d_in[7];
    const float* bo = (const float*)d_in[8];
    float* out = (float*)d_out;

    // ws layout (ushort units), 40MB total. Cxb ALIASES xb (xb dead after
    // gemm_qkv; attn writes Cxb, gemm_out reads it).
    unsigned short* base = (unsigned short*)d_ws;
    unsigned short* Wot   = base;                   //  0M .. 1M
    unsigned short* Qb    = base + 1 * MEG;         //  1M .. 5M
    unsigned short* Kb    = base + 5 * MEG;         //  5M .. 9M
    unsigned short* Vt    = base + 9 * MEG;         //  9M ..13M
    unsigned short* xb    = base + 13 * MEG;        // 13M ..17M
    unsigned short* Wqt   = base + 17 * MEG;        // 17M ..18M
    unsigned short* Wkt   = base + 18 * MEG;        // 18M ..19M
    unsigned short* Wvt   = base + 19 * MEG;        // 19M ..20M
    unsigned short* Cxb   = xb;                     // aliases xb

    prep<<<dim3(32, 32, 5), dim3(32, 8), 0, stream>>>(
        x, xb, Wq, Wk, Wv, Wo, Wqt, Wkt, Wvt, Wot);

    gemm_qkv<<<dim3(D_MODEL / 128, M_ROWS / 128, 3), dim3(256), 0, stream>>>(
        xb, Wqt, Wkt, Wvt, bq, bk, bv, Qb, Kb, Vt);

    attn_mfma<<<dim3(S_LEN / 128, BHEADS), dim3(256), 0, stream>>>(
        Qb, Kb, Vt, Cxb);

    gemm_out<<<dim3(D_MODEL / 128, M_ROWS / 64), dim3(256), 0, stream>>>(
        Cxb, Wot, bo, out);
}